// Round 1
// baseline (882.616 us; speedup 1.0000x reference)
//
#include <hip/hip_runtime.h>
#include <math.h>

#define KK 128
#define TT 512
#define BB 512
#define TAG_START 126
#define TAG_STOP 127
#define NEGV -10000.0f

// ws layout (floats):
//   E    : [0, 16384)        exp(trans[j,k] - M_j), row-major
//   M    : [16384, 16512)    per-row max of trans
//   fwd  : [16512, 17024)    forward scores per batch
//   gold : [17024, 17536)    gold scores per batch

__global__ __launch_bounds__(128) void prep_kernel(const float* __restrict__ trans,
                                                   float* __restrict__ E,
                                                   float* __restrict__ M) {
    __shared__ float tr[KK * KK];
    int tid = threadIdx.x;
    for (int idx = tid; idx < KK * KK; idx += 128) tr[idx] = trans[idx];
    __syncthreads();
    int j = tid;
    float m = tr[j * KK];
    for (int k = 1; k < KK; k++) m = fmaxf(m, tr[j * KK + k]);
    M[j] = m;
    for (int k = 0; k < KK; k++) E[j * KK + k] = __expf(tr[j * KK + k] - m);
}

__global__ __launch_bounds__(128, 2) void fwd_kernel(
    const float* __restrict__ feats, const float* __restrict__ trans,
    const float* __restrict__ E, const float* __restrict__ M,
    const int* __restrict__ lengths, float* __restrict__ fwd_out) {
    int b = blockIdx.x;
    int j = threadIdx.x;
    __shared__ __align__(16) float a_s[KK];
    __shared__ float As;
    __shared__ float red[4];

    // E row j -> registers (fully unrolled, static indexing => stays in VGPRs)
    float Erow[KK];
    const float4* E4 = (const float4*)(E + j * KK);
#pragma unroll
    for (int q = 0; q < KK / 4; q++) {
        float4 v = E4[q];
        Erow[4 * q + 0] = v.x;
        Erow[4 * q + 1] = v.y;
        Erow[4 * q + 2] = v.z;
        Erow[4 * q + 3] = v.w;
    }
    float Mj = M[j];
    int len = lengths[b];
    const float* fb = feats + (size_t)b * TT * KK + j;

    float alpha = (j == TAG_START) ? 0.0f : NEGV;
    float A = 0.0f;  // exact max of alpha0

    for (int t = 0; t < len; t++) {
        float em = fb[(size_t)t * KK];      // issue early; consumed after inner loop
        a_s[j] = __expf(alpha - A);         // prior-iter reads fenced by loop-end barrier
        __syncthreads();
        const float4* a4 = (const float4*)a_s;
        float y0 = 0.f, y1 = 0.f, y2 = 0.f, y3 = 0.f;
#pragma unroll
        for (int q = 0; q < KK / 4; q++) {
            float4 av = a4[q];              // broadcast LDS read
            y0 = fmaf(Erow[4 * q + 0], av.x, y0);
            y1 = fmaf(Erow[4 * q + 1], av.y, y1);
            y2 = fmaf(Erow[4 * q + 2], av.z, y2);
            y3 = fmaf(Erow[4 * q + 3], av.w, y3);
        }
        float y = (y0 + y1) + (y2 + y3);
        alpha = em + Mj + A + __logf(y);
        if (j == 0) As = alpha;             // shift for next step (lane-uniform proxy of max)
        __syncthreads();                    // also fences a_s reads vs next-iter writes
        A = As;
    }

    // terminal: term[j] = alpha[j] + trans[STOP, j]; forward = logsumexp_j(term)
    float term = alpha + trans[TAG_STOP * KK + j];
    float m = term;
#pragma unroll
    for (int off = 32; off >= 1; off >>= 1) m = fmaxf(m, __shfl_xor(m, off));
    if ((j & 63) == 0) red[j >> 6] = m;
    __syncthreads();
    m = fmaxf(red[0], red[1]);
    float s = __expf(term - m);
#pragma unroll
    for (int off = 32; off >= 1; off >>= 1) s += __shfl_xor(s, off);
    if ((j & 63) == 0) red[2 + (j >> 6)] = s;
    __syncthreads();
    if (j == 0) fwd_out[b] = m + __logf(red[2] + red[3]);
}

__global__ __launch_bounds__(256) void gold_kernel(
    const float* __restrict__ feats, const float* __restrict__ trans,
    const int* __restrict__ tags, const int* __restrict__ lengths,
    float* __restrict__ gold_out) {
    int b = blockIdx.x;
    int tid = threadIdx.x;
    int len = lengths[b];
    const int* tg = tags + b * TT;
    const float* fb = feats + (size_t)b * TT * KK;
    float acc = 0.f;
    // transition terms: i in [0, len], from=(i==0?START:tags[i-1]), to=(i<len?tags[i]:STOP)
    for (int i = tid; i <= len; i += 256) {
        int from = (i == 0) ? TAG_START : tg[i - 1];
        int to = (i < len) ? tg[i] : TAG_STOP;
        acc += trans[to * KK + from];
    }
    // emission terms: t < len
    for (int t = tid; t < len; t += 256) {
        acc += fb[(size_t)t * KK + tg[t]];
    }
    __shared__ float sred[4];
#pragma unroll
    for (int off = 32; off >= 1; off >>= 1) acc += __shfl_xor(acc, off);
    if ((tid & 63) == 0) sred[tid >> 6] = acc;
    __syncthreads();
    if (tid == 0) gold_out[b] = (sred[0] + sred[1]) + (sred[2] + sred[3]);
}

__global__ __launch_bounds__(512) void final_kernel(const float* __restrict__ fwd_s,
                                                    const float* __restrict__ gold_s,
                                                    float* __restrict__ out) {
    int tid = threadIdx.x;
    float v = fabsf(fwd_s[tid] - gold_s[tid]);
#pragma unroll
    for (int off = 32; off >= 1; off >>= 1) v += __shfl_xor(v, off);
    __shared__ float sred[8];
    if ((tid & 63) == 0) sred[tid >> 6] = v;
    __syncthreads();
    if (tid == 0) {
        float s = 0.f;
        for (int i = 0; i < 8; i++) s += sred[i];
        out[0] = s / (float)BB;
    }
}

extern "C" void kernel_launch(void* const* d_in, const int* in_sizes, int n_in,
                              void* d_out, int out_size, void* d_ws, size_t ws_size,
                              hipStream_t stream) {
    const float* feats = (const float*)d_in[0];
    const float* trans = (const float*)d_in[1];
    const int* tags = (const int*)d_in[2];
    const int* lengths = (const int*)d_in[3];

    float* ws = (float*)d_ws;
    float* E = ws;
    float* M = ws + 16384;
    float* fwdv = ws + 16384 + 128;
    float* goldv = fwdv + BB;

    prep_kernel<<<1, 128, 0, stream>>>(trans, E, M);
    fwd_kernel<<<BB, 128, 0, stream>>>(feats, trans, E, M, lengths, fwdv);
    gold_kernel<<<BB, 256, 0, stream>>>(feats, trans, tags, lengths, goldv);
    final_kernel<<<1, 512, 0, stream>>>(fwdv, goldv, (float*)d_out);
}

// Round 2
// 752.125 us; speedup vs baseline: 1.1735x; 1.1735x over previous
//
#include <hip/hip_runtime.h>
#include <math.h>

#define KK 128
#define TT 512
#define BB 512
#define TAG_START 126
#define TAG_STOP 127
#define NEGV -10000.0f

// ws layout (floats):
//   E    : [0, 16384)        exp(trans[j,k] - M_j), row-major
//   M    : [16384, 16512)    per-row max of trans
//   fwd  : [16512, 17024)    forward scores per batch
//   gold : [17024, 17536)    gold scores per batch

__global__ __launch_bounds__(128) void prep_kernel(const float* __restrict__ trans,
                                                   float* __restrict__ E,
                                                   float* __restrict__ M) {
    int j = blockIdx.x;      // 128 blocks, one row each
    int k = threadIdx.x;
    float v = trans[j * KK + k];
    float m = v;
#pragma unroll
    for (int off = 32; off >= 1; off >>= 1) m = fmaxf(m, __shfl_xor(m, off));
    __shared__ float red[2];
    if ((k & 63) == 0) red[k >> 6] = m;
    __syncthreads();
    m = fmaxf(red[0], red[1]);
    if (k == 0) M[j] = m;
    E[j * KK + k] = __expf(v - m);
}

// 256 threads: thread (j = tid&127, h = tid>>7) owns half-row E[j][64h..64h+63]
// in 64 VGPRs. x broadcast from LDS; split-K partials reduced via LDS.
__global__ __launch_bounds__(256, 2) void fwd_kernel(
    const float* __restrict__ feats, const float* __restrict__ trans,
    const float* __restrict__ E, const float* __restrict__ M,
    const int* __restrict__ lengths, float* __restrict__ fwd_out) {
    int b = blockIdx.x;
    int tid = threadIdx.x;
    int j = tid & 127;
    int h = tid >> 7;

    __shared__ __align__(16) float x_s[KK];
    __shared__ float part[256];
    __shared__ float As2[2];
    __shared__ float red[4];

    // 64-float half-row -> registers (static indexing, ~90 VGPR total)
    float Erow[64];
    const float4* E4 = (const float4*)(E + j * KK + 64 * h);
#pragma unroll
    for (int q = 0; q < 16; q++) {
        float4 v = E4[q];
        Erow[4 * q + 0] = v.x;
        Erow[4 * q + 1] = v.y;
        Erow[4 * q + 2] = v.z;
        Erow[4 * q + 3] = v.w;
    }
    float Mj = M[j];
    int len = lengths[b];
    const float* fb = feats + (size_t)b * TT * KK + j;

    // init: x(0) = exp(alpha0 - 0); As2[1] = S(1) init
    if (h == 0) x_s[j] = (j == TAG_START) ? 1.0f : 0.0f;
    if (tid == 0) { As2[0] = 0.0f; As2[1] = 0.0f; }
    __syncthreads();

    float A = 0.0f;                       // shift S(t) used to build x(t)
    float alpha = 0.0f;                   // live in h0 threads
    float em = (h == 0) ? fb[0] : 0.0f;   // emission for t=0

    for (int t = 0; t < len; t++) {
        // software-pipeline next emission (hides global latency under the dot)
        float em_next = 0.0f;
        if (h == 0 && t + 1 < len) em_next = fb[(size_t)(t + 1) * KK];

        // partial dot over this thread's 64-k half (x reads are wave-uniform -> broadcast)
        const float4* x4 = (const float4*)(x_s + 64 * h);
        float y0 = 0.f, y1 = 0.f, y2 = 0.f, y3 = 0.f;
#pragma unroll
        for (int q = 0; q < 16; q++) {
            float4 xv = x4[q];
            y0 = fmaf(Erow[4 * q + 0], xv.x, y0);
            y1 = fmaf(Erow[4 * q + 1], xv.y, y1);
            y2 = fmaf(Erow[4 * q + 2], xv.z, y2);
            y3 = fmaf(Erow[4 * q + 3], xv.w, y3);
        }
        part[tid] = (y0 + y1) + (y2 + y3);
        __syncthreads();                  // partials ready; h1 done reading x_s

        if (h == 0) {
            float Sn = As2[(t + 1) & 1];  // alpha_0(t-1): shift for x(t+1)
            float y = part[tid] + part[tid + 128];
            alpha = em + Mj + A + __logf(y);
            if (tid == 0) As2[t & 1] = alpha;   // becomes shift two steps later
            x_s[j] = __expf(alpha - Sn);
            A = Sn;
        }
        em = em_next;
        __syncthreads();                  // x(t+1) visible to all
    }

    // terminal logsumexp over j of alpha_j + trans[STOP, j] (alpha lives in h0)
    float term = (h == 0) ? (alpha + trans[TAG_STOP * KK + j]) : -1e30f;
    float m = term;
#pragma unroll
    for (int off = 32; off >= 1; off >>= 1) m = fmaxf(m, __shfl_xor(m, off));
    int wv = tid >> 6;
    if ((tid & 63) == 0) red[wv] = m;
    __syncthreads();
    m = fmaxf(red[0], red[1]);
    float s = (h == 0) ? __expf(term - m) : 0.0f;
#pragma unroll
    for (int off = 32; off >= 1; off >>= 1) s += __shfl_xor(s, off);
    __syncthreads();                      // red[] reuse fence
    if ((tid & 63) == 0) red[wv] = s;
    __syncthreads();
    if (tid == 0) fwd_out[b] = m + __logf(red[0] + red[1]);
}

__global__ __launch_bounds__(256) void gold_kernel(
    const float* __restrict__ feats, const float* __restrict__ trans,
    const int* __restrict__ tags, const int* __restrict__ lengths,
    float* __restrict__ gold_out) {
    int b = blockIdx.x;
    int tid = threadIdx.x;
    int len = lengths[b];
    const int* tg = tags + b * TT;
    const float* fb = feats + (size_t)b * TT * KK;
    float acc = 0.f;
    for (int i = tid; i <= len; i += 256) {
        int from = (i == 0) ? TAG_START : tg[i - 1];
        int to = (i < len) ? tg[i] : TAG_STOP;
        acc += trans[to * KK + from];
    }
    for (int t = tid; t < len; t += 256) {
        acc += fb[(size_t)t * KK + tg[t]];
    }
    __shared__ float sred[4];
#pragma unroll
    for (int off = 32; off >= 1; off >>= 1) acc += __shfl_xor(acc, off);
    if ((tid & 63) == 0) sred[tid >> 6] = acc;
    __syncthreads();
    if (tid == 0) gold_out[b] = (sred[0] + sred[1]) + (sred[2] + sred[3]);
}

__global__ __launch_bounds__(512) void final_kernel(const float* __restrict__ fwd_s,
                                                    const float* __restrict__ gold_s,
                                                    float* __restrict__ out) {
    int tid = threadIdx.x;
    float v = fabsf(fwd_s[tid] - gold_s[tid]);
#pragma unroll
    for (int off = 32; off >= 1; off >>= 1) v += __shfl_xor(v, off);
    __shared__ float sred[8];
    if ((tid & 63) == 0) sred[tid >> 6] = v;
    __syncthreads();
    if (tid == 0) {
        float s = 0.f;
        for (int i = 0; i < 8; i++) s += sred[i];
        out[0] = s / (float)BB;
    }
}

extern "C" void kernel_launch(void* const* d_in, const int* in_sizes, int n_in,
                              void* d_out, int out_size, void* d_ws, size_t ws_size,
                              hipStream_t stream) {
    const float* feats = (const float*)d_in[0];
    const float* trans = (const float*)d_in[1];
    const int* tags = (const int*)d_in[2];
    const int* lengths = (const int*)d_in[3];

    float* ws = (float*)d_ws;
    float* E = ws;
    float* M = ws + 16384;
    float* fwdv = ws + 16384 + 128;
    float* goldv = fwdv + BB;

    prep_kernel<<<KK, 128, 0, stream>>>(trans, E, M);
    fwd_kernel<<<BB, 256, 0, stream>>>(feats, trans, E, M, lengths, fwdv);
    gold_kernel<<<BB, 256, 0, stream>>>(feats, trans, tags, lengths, goldv);
    final_kernel<<<1, 512, 0, stream>>>(fwdv, goldv, (float*)d_out);
}

// Round 3
// 604.001 us; speedup vs baseline: 1.4613x; 1.2452x over previous
//
#include <hip/hip_runtime.h>
#include <math.h>

#define KK 128
#define TT 512
#define BB 512
#define TAG_START 126
#define TAG_STOP 127

typedef float v4f __attribute__((ext_vector_type(4)));

// ws layout (floats): fwd [0,512), gold [512,1024)

// Blocks 0..511: forward recursion for batch b = blockIdx.x.
//   256 threads = 4 waves. Wave w, lane l: row = 32w + (l&31), k-half = l>>5.
//   Each thread holds E[row][64*half .. +63] in 64 VGPRs (pinned via volatile asm
//   loads + in-register exp — not re-loadable, not rematerializable).
//   Per step: 64 FMAs + shfl cross-half reduce + log/exp + ONE barrier
//   (x double-buffered in LDS).
// Blocks 512..1023: gold score for batch b-512 (backfills idle CUs).
__global__ __launch_bounds__(256, 2) void fused_kernel(
    const float* __restrict__ feats, const float* __restrict__ trans,
    const int* __restrict__ tags, const int* __restrict__ lengths,
    float* __restrict__ fwd_out, float* __restrict__ gold_out) {
    int tid = threadIdx.x;

    if (blockIdx.x < BB) {
        // ---------------- forward path ----------------
        int b = blockIdx.x;
        int w = tid >> 6;       // wave 0..3
        int l = tid & 63;
        int half = l >> 5;      // k-half 0/1
        int row = 32 * w + (l & 31);

        __shared__ __align__(16) float xs[2][KK];
        __shared__ float As[2];
        __shared__ float redm[4], reds[4];

        // --- pin trans row-half in VGPRs via volatile asm ---
        const float* tp = trans + row * KK + 64 * half;
        v4f tv[16];
#pragma unroll
        for (int q = 0; q < 16; q++) {
            asm volatile("global_load_dwordx4 %0, %1, off"
                         : "=v"(tv[q]) : "v"(tp + 4 * q));
        }
        int len = lengths[b];
        const float* fb = feats + (size_t)b * TT * KK + row;
        // tie the wait to every result so no use can be scheduled before it
        asm volatile("s_waitcnt vmcnt(0)"
                     : "+v"(tv[0]), "+v"(tv[1]), "+v"(tv[2]), "+v"(tv[3]),
                       "+v"(tv[4]), "+v"(tv[5]), "+v"(tv[6]), "+v"(tv[7]),
                       "+v"(tv[8]), "+v"(tv[9]), "+v"(tv[10]), "+v"(tv[11]),
                       "+v"(tv[12]), "+v"(tv[13]), "+v"(tv[14]), "+v"(tv[15]));

        float m64 = -1e30f;
#pragma unroll
        for (int q = 0; q < 16; q++)
            m64 = fmaxf(m64, fmaxf(fmaxf(tv[q].x, tv[q].y), fmaxf(tv[q].z, tv[q].w)));
        float Mj = fmaxf(m64, __shfl_xor(m64, 32));   // full-row max

        float Erow[64];                                // exp results: 64 live VGPRs
#pragma unroll
        for (int q = 0; q < 16; q++) {
            Erow[4 * q + 0] = __expf(tv[q].x - Mj);
            Erow[4 * q + 1] = __expf(tv[q].y - Mj);
            Erow[4 * q + 2] = __expf(tv[q].z - Mj);
            Erow[4 * q + 3] = __expf(tv[q].w - Mj);
        }

        // init: x(0) = exp(alpha0), shift 0
        if (tid < KK) xs[0][tid] = (tid == TAG_START) ? 1.0f : 0.0f;
        if (tid == 0) { As[0] = 0.f; As[1] = 0.f; }
        __syncthreads();

        float A = 0.f;          // shift of current x buffer
        float alpha = 0.f;
        float em = fb[0];

        for (int t = 0; t < len; t++) {
            int cur = t & 1, nxt = cur ^ 1;
            float Sn = As[nxt];                        // alpha(t-1)[0], shift for x(t+1)
            float em_next = (t + 1 < len) ? fb[(size_t)(t + 1) * KK] : 0.f;

            const v4f* x4 = (const v4f*)(xs[cur] + 64 * half);
            float y0 = 0.f, y1 = 0.f, y2 = 0.f, y3 = 0.f;
#pragma unroll
            for (int q = 0; q < 16; q++) {
                v4f xv = x4[q];                        // 2-address broadcast read
                y0 = fmaf(Erow[4 * q + 0], xv.x, y0);
                y1 = fmaf(Erow[4 * q + 1], xv.y, y1);
                y2 = fmaf(Erow[4 * q + 2], xv.z, y2);
                y3 = fmaf(Erow[4 * q + 3], xv.w, y3);
            }
            float y64 = (y0 + y1) + (y2 + y3);
            float y = y64 + __shfl_xor(y64, 32);       // combine k-halves (same row)
            alpha = em + Mj + A + __logf(y);
            if (half == 0) xs[nxt][row] = __expf(alpha - Sn);
            if (tid == 0) As[cur] = alpha;             // shift used at step t+1
            A = Sn;
            em = em_next;
            __syncthreads();                           // single barrier per step
        }

        // terminal logsumexp_j( alpha[j] + trans[STOP, j] )
        float term = (half == 0) ? (alpha + trans[TAG_STOP * KK + row]) : -1e30f;
        float m = term;
#pragma unroll
        for (int off = 32; off >= 1; off >>= 1) m = fmaxf(m, __shfl_xor(m, off));
        float s = (half == 0) ? __expf(term - m) : 0.f;
#pragma unroll
        for (int off = 32; off >= 1; off >>= 1) s += __shfl_xor(s, off);
        if (l == 0) { redm[w] = m; reds[w] = s; }
        __syncthreads();
        if (tid == 0) {
            float M2 = fmaxf(fmaxf(redm[0], redm[1]), fmaxf(redm[2], redm[3]));
            float S2 = 0.f;
            for (int i = 0; i < 4; i++) S2 += reds[i] * __expf(redm[i] - M2);
            fwd_out[b] = M2 + __logf(S2);
        }
    } else {
        // ---------------- gold path ----------------
        int b = blockIdx.x - BB;
        int len = lengths[b];
        const int* tg = tags + b * TT;
        const float* fb = feats + (size_t)b * TT * KK;
        float acc = 0.f;
        for (int i = tid; i <= len; i += 256) {
            int from = (i == 0) ? TAG_START : tg[i - 1];
            int to = (i < len) ? tg[i] : TAG_STOP;
            acc += trans[to * KK + from];
        }
        for (int t = tid; t < len; t += 256)
            acc += fb[(size_t)t * KK + tg[t]];
        __shared__ float sred[4];
#pragma unroll
        for (int off = 32; off >= 1; off >>= 1) acc += __shfl_xor(acc, off);
        if ((tid & 63) == 0) sred[tid >> 6] = acc;
        __syncthreads();
        if (tid == 0) gold_out[b] = (sred[0] + sred[1]) + (sred[2] + sred[3]);
    }
}

__global__ __launch_bounds__(512) void final_kernel(const float* __restrict__ fwd_s,
                                                    const float* __restrict__ gold_s,
                                                    float* __restrict__ out) {
    int tid = threadIdx.x;
    float v = fabsf(fwd_s[tid] - gold_s[tid]);
#pragma unroll
    for (int off = 32; off >= 1; off >>= 1) v += __shfl_xor(v, off);
    __shared__ float sred[8];
    if ((tid & 63) == 0) sred[tid >> 6] = v;
    __syncthreads();
    if (tid == 0) {
        float s = 0.f;
        for (int i = 0; i < 8; i++) s += sred[i];
        out[0] = s / (float)BB;
    }
}

extern "C" void kernel_launch(void* const* d_in, const int* in_sizes, int n_in,
                              void* d_out, int out_size, void* d_ws, size_t ws_size,
                              hipStream_t stream) {
    const float* feats = (const float*)d_in[0];
    const float* trans = (const float*)d_in[1];
    const int* tags = (const int*)d_in[2];
    const int* lengths = (const int*)d_in[3];

    float* ws = (float*)d_ws;
    float* fwdv = ws;
    float* goldv = ws + BB;

    fused_kernel<<<2 * BB, 256, 0, stream>>>(feats, trans, tags, lengths, fwdv, goldv);
    final_kernel<<<1, 512, 0, stream>>>(fwdv, goldv, (float*)d_out);
}

// Round 4
// 431.372 us; speedup vs baseline: 2.0461x; 1.4002x over previous
//
#include <hip/hip_runtime.h>
#include <math.h>

#define KK 128
#define TT 512
#define BB 512
#define TAG_START 126
#define TAG_STOP 127

typedef float v4f __attribute__((ext_vector_type(4)));

// ws layout (floats): fwd [0,512), gold [512,1024)

// Blocks 0..511: forward recursion for batch b.
//   512 threads = 8 waves. wave w: rg=w>>1 (row group), kp=w&1 (k half).
//   lane l: row = 32*rg + (l&31), k-quarter kq = 2*kp + (l>>5).
//   Thread holds E[row][32*kq .. +32) in 32 VGPRs (volatile-asm pinned).
//   Per step: 8 ds_read_b128 (broadcast) + 32 FMA, shfl_xor(32) quarter-pair
//   reduce, LDS part2[row][kp] exchange, redundant per-row epilogue, 2 barriers.
//   em prefetched 8 steps ahead in a rolling register buffer (hides HBM ~900cy).
// Blocks 512..1023: gold score for batch b-512.
__global__ __launch_bounds__(512, 4) void fused_kernel(
    const float* __restrict__ feats, const float* __restrict__ trans,
    const int* __restrict__ tags, const int* __restrict__ lengths,
    float* __restrict__ fwd_out, float* __restrict__ gold_out) {
    int tid = threadIdx.x;

    if (blockIdx.x < BB) {
        // ---------------- forward path ----------------
        int b = blockIdx.x;
        int w = tid >> 6;
        int l = tid & 63;
        int rg = w >> 1;
        int kp = w & 1;
        int row = 32 * rg + (l & 31);
        int kq = 2 * kp + (l >> 5);

        __shared__ __align__(16) float xs[KK];
        __shared__ __align__(16) float part2[KK][2];
        __shared__ __align__(16) float mp[KK][2];
        __shared__ float As[2];
        __shared__ float redm[4], reds[4];

        // --- pin E quarter-row (32 floats) via volatile asm loads ---
        const float* tp = trans + row * KK + 32 * kq;
        v4f tv[8];
#pragma unroll
        for (int q = 0; q < 8; q++) {
            asm volatile("global_load_dwordx4 %0, %1, off"
                         : "=v"(tv[q]) : "v"(tp + 4 * q));
        }
        int len = lengths[b];
        const float* fbr = feats + (size_t)b * TT * KK + row;
        asm volatile("s_waitcnt vmcnt(0)"
                     : "+v"(tv[0]), "+v"(tv[1]), "+v"(tv[2]), "+v"(tv[3]),
                       "+v"(tv[4]), "+v"(tv[5]), "+v"(tv[6]), "+v"(tv[7]));

        // full-row max: 32-local -> quarter-pair (shfl 32) -> cross-kp via LDS
        float m32 = -1e30f;
#pragma unroll
        for (int q = 0; q < 8; q++)
            m32 = fmaxf(m32, fmaxf(fmaxf(tv[q].x, tv[q].y), fmaxf(tv[q].z, tv[q].w)));
        float m64 = fmaxf(m32, __shfl_xor(m32, 32));
        if (l < 32) mp[row][kp] = m64;
        if (tid == 0) { As[0] = 0.f; As[1] = 0.f; }
        __syncthreads();
        float2 mv = *(const float2*)mp[row];
        float Mj = fmaxf(mv.x, mv.y);

        float Erow[32];
#pragma unroll
        for (int q = 0; q < 8; q++) {
            Erow[4 * q + 0] = __expf(tv[q].x - Mj);
            Erow[4 * q + 1] = __expf(tv[q].y - Mj);
            Erow[4 * q + 2] = __expf(tv[q].z - Mj);
            Erow[4 * q + 3] = __expf(tv[q].w - Mj);
        }
        if (kp == 0 && l < 32) xs[row] = (row == TAG_START) ? 1.0f : 0.0f;
        __syncthreads();

        float alpha = 0.f, A = 0.f;
        // rolling 8-deep emission prefetch
        float emb[8];
#pragma unroll
        for (int d = 0; d < 8; d++) {
            int tf = (d < len) ? d : (len - 1);
            emb[d] = fbr[(size_t)tf * KK];
        }

        int tmax = (len + 7) & ~7;
        for (int t0 = 0; t0 < tmax; t0 += 8) {
#pragma unroll
            for (int d = 0; d < 8; d++) {
                int t = t0 + d;
                if (t < len) {                        // block-uniform guard
                    float em = emb[d];
                    int tf = (t + 8 < len) ? (t + 8) : (len - 1);
                    emb[d] = fbr[(size_t)tf * KK];    // issue 8 steps ahead

                    const v4f* x4 = (const v4f*)(xs + 32 * kq);
                    float y0 = 0.f, y1 = 0.f, y2 = 0.f, y3 = 0.f;
#pragma unroll
                    for (int q = 0; q < 8; q++) {
                        v4f xv = x4[q];               // broadcast LDS read
                        y0 = fmaf(Erow[4 * q + 0], xv.x, y0);
                        y1 = fmaf(Erow[4 * q + 1], xv.y, y1);
                        y2 = fmaf(Erow[4 * q + 2], xv.z, y2);
                        y3 = fmaf(Erow[4 * q + 3], xv.w, y3);
                    }
                    float yq = (y0 + y1) + (y2 + y3);
                    float yh = yq + __shfl_xor(yq, 32);   // quarter pair
                    if (l < 32) part2[row][kp] = yh;
                    __syncthreads();

                    float2 pp = *(const float2*)part2[row];
                    float Sn = As[(t + 1) & 1];       // alpha_0(t-1)
                    alpha = em + Mj + A + __logf(pp.x + pp.y);
                    if (kp == 0 && l < 32) xs[row] = __expf(alpha - Sn);
                    if (tid == 0) As[t & 1] = alpha;
                    A = Sn;
                    __syncthreads();
                }
            }
        }

        // terminal logsumexp_j( alpha[j] + trans[STOP, j] ) — rows unique on
        // waves 0,2,4,6 lanes<32; other lanes contribute -inf/0
        if (kp == 0) {
            float term = (l < 32) ? (alpha + trans[TAG_STOP * KK + row]) : -1e30f;
            float m = term;
#pragma unroll
            for (int off = 32; off >= 1; off >>= 1) m = fmaxf(m, __shfl_xor(m, off));
            float s = __expf(term - m);               // -1e30 lanes -> 0
#pragma unroll
            for (int off = 32; off >= 1; off >>= 1) s += __shfl_xor(s, off);
            if (l == 0) { redm[rg] = m; reds[rg] = s; }
        }
        __syncthreads();
        if (tid == 0) {
            float M2 = fmaxf(fmaxf(redm[0], redm[1]), fmaxf(redm[2], redm[3]));
            float S2 = 0.f;
            for (int i = 0; i < 4; i++) S2 += reds[i] * __expf(redm[i] - M2);
            fwd_out[b] = M2 + __logf(S2);
        }
    } else {
        // ---------------- gold path ----------------
        int b = blockIdx.x - BB;
        int len = lengths[b];
        const int* tg = tags + b * TT;
        const float* fb = feats + (size_t)b * TT * KK;
        float acc = 0.f;
        for (int i = tid; i <= len; i += 512) {
            int from = (i == 0) ? TAG_START : tg[i - 1];
            int to = (i < len) ? tg[i] : TAG_STOP;
            acc += trans[to * KK + from];
        }
        for (int t = tid; t < len; t += 512)
            acc += fb[(size_t)t * KK + tg[t]];
        __shared__ float sred[8];
#pragma unroll
        for (int off = 32; off >= 1; off >>= 1) acc += __shfl_xor(acc, off);
        if ((tid & 63) == 0) sred[tid >> 6] = acc;
        __syncthreads();
        if (tid == 0) {
            float s = 0.f;
            for (int i = 0; i < 8; i++) s += sred[i];
            gold_out[b] = s;
        }
    }
}

__global__ __launch_bounds__(512) void final_kernel(const float* __restrict__ fwd_s,
                                                    const float* __restrict__ gold_s,
                                                    float* __restrict__ out) {
    int tid = threadIdx.x;
    float v = fabsf(fwd_s[tid] - gold_s[tid]);
#pragma unroll
    for (int off = 32; off >= 1; off >>= 1) v += __shfl_xor(v, off);
    __shared__ float sred[8];
    if ((tid & 63) == 0) sred[tid >> 6] = v;
    __syncthreads();
    if (tid == 0) {
        float s = 0.f;
        for (int i = 0; i < 8; i++) s += sred[i];
        out[0] = s / (float)BB;
    }
}

extern "C" void kernel_launch(void* const* d_in, const int* in_sizes, int n_in,
                              void* d_out, int out_size, void* d_ws, size_t ws_size,
                              hipStream_t stream) {
    const float* feats = (const float*)d_in[0];
    const float* trans = (const float*)d_in[1];
    const int* tags = (const int*)d_in[2];
    const int* lengths = (const int*)d_in[3];

    float* ws = (float*)d_ws;
    float* fwdv = ws;
    float* goldv = ws + BB;

    fused_kernel<<<2 * BB, 512, 0, stream>>>(feats, trans, tags, lengths, fwdv, goldv);
    final_kernel<<<1, 512, 0, stream>>>(fwdv, goldv, (float*)d_out);
}

// Round 5
// 397.754 us; speedup vs baseline: 2.2190x; 1.0845x over previous
//
#include <hip/hip_runtime.h>
#include <math.h>

#define KK 128
#define TT 512
#define BB 512
#define TAG_START 126
#define TAG_STOP 127

typedef float v4f __attribute__((ext_vector_type(4)));

// padded x index: quarter q (rows/k 32q..32q+31) starts at float 40q ->
// quarter base banks {0,8,16,24}: the 4 distinct b128 addresses per wave hit
// disjoint bank groups => conflict-free broadcast reads.
#define XIDX(r) ((r) + (((r) >> 5) << 3))

// ws layout (floats): fwd [0,512), gold [512,1024)

// Blocks 0..511: forward recursion for batch b.
//   512 threads = 8 waves. wave w, lane l: row = 16w + (l&15), kq = l>>4.
//   Thread holds E[row][32*kq..+32) in 32 regs (volatile-asm pinned; lands in
//   AGPR side of the unified file — VALU reads AGPRs directly, acceptable).
//   Full-row K reduce is INTRA-wave: shfl_xor(16) + shfl_xor(32) (lanes
//   {l,l^16,l^32,l^48} = same row, 4 quarters). ONE barrier per step; xs
//   double-buffered; epilogue redundant in all lanes. em prefetch depth 8.
// Blocks 512..1023: gold score for batch b-512.
__global__ __launch_bounds__(512, 4) void fused_kernel(
    const float* __restrict__ feats, const float* __restrict__ trans,
    const int* __restrict__ tags, const int* __restrict__ lengths,
    float* __restrict__ fwd_out, float* __restrict__ gold_out) {
    int tid = threadIdx.x;

    if (blockIdx.x < BB) {
        // ---------------- forward path ----------------
        int b = blockIdx.x;
        int w = tid >> 6;
        int l = tid & 63;
        int row = 16 * w + (l & 15);
        int kq = l >> 4;

        __shared__ __align__(16) float xs[2][160];   // padded (XIDX)
        __shared__ float As[2];
        __shared__ float redm[8], reds[8];

        // --- pin E quarter-row (32 floats) via volatile asm loads ---
        const float* tp = trans + row * KK + 32 * kq;
        v4f tv[8];
#pragma unroll
        for (int q = 0; q < 8; q++) {
            asm volatile("global_load_dwordx4 %0, %1, off"
                         : "=v"(tv[q]) : "v"(tp + 4 * q));
        }
        int len = lengths[b];
        const float* fbr = feats + (size_t)b * TT * KK + row;
        asm volatile("s_waitcnt vmcnt(0)"
                     : "+v"(tv[0]), "+v"(tv[1]), "+v"(tv[2]), "+v"(tv[3]),
                       "+v"(tv[4]), "+v"(tv[5]), "+v"(tv[6]), "+v"(tv[7]));

        // full-row max entirely in-wave
        float m32 = -1e30f;
#pragma unroll
        for (int q = 0; q < 8; q++)
            m32 = fmaxf(m32, fmaxf(fmaxf(tv[q].x, tv[q].y), fmaxf(tv[q].z, tv[q].w)));
        m32 = fmaxf(m32, __shfl_xor(m32, 16));
        float Mj = fmaxf(m32, __shfl_xor(m32, 32));

        float Erow[32];
#pragma unroll
        for (int q = 0; q < 8; q++) {
            Erow[4 * q + 0] = __expf(tv[q].x - Mj);
            Erow[4 * q + 1] = __expf(tv[q].y - Mj);
            Erow[4 * q + 2] = __expf(tv[q].z - Mj);
            Erow[4 * q + 3] = __expf(tv[q].w - Mj);
        }

        // init x(0) = exp(alpha0 - 0); each (w, l<16) pair owns one row
        if (l < 16) xs[0][XIDX(row)] = (row == TAG_START) ? 1.0f : 0.0f;
        if (tid == 0) { As[0] = 0.f; As[1] = 0.f; }

        float alpha = 0.f, A = 0.f;
        // rolling 8-deep emission prefetch (hides ~900cy HBM miss latency)
        float emb[8];
#pragma unroll
        for (int d = 0; d < 8; d++) {
            int tf = (d < len) ? d : (len - 1);
            emb[d] = fbr[(size_t)tf * KK];
        }
        __syncthreads();

        int tmax = (len + 7) & ~7;
        for (int t0 = 0; t0 < tmax; t0 += 8) {
#pragma unroll
            for (int d = 0; d < 8; d++) {
                int t = t0 + d;
                if (t < len) {                       // block-uniform guard
                    float em = emb[d];
                    int tf = (t + 8 < len) ? (t + 8) : (len - 1);
                    emb[d] = fbr[(size_t)tf * KK];   // issue 8 steps ahead

                    int cur = t & 1, nxt = cur ^ 1;
                    float Sn = As[nxt];              // alpha_0(t-1): shift of x(t+1)
                    const v4f* x4 = (const v4f*)(xs[cur] + 40 * kq);
                    float y0 = 0.f, y1 = 0.f, y2 = 0.f, y3 = 0.f;
#pragma unroll
                    for (int q = 0; q < 8; q++) {
                        v4f xv = x4[q];              // broadcast, bank-disjoint
                        y0 = fmaf(Erow[4 * q + 0], xv.x, y0);
                        y1 = fmaf(Erow[4 * q + 1], xv.y, y1);
                        y2 = fmaf(Erow[4 * q + 2], xv.z, y2);
                        y3 = fmaf(Erow[4 * q + 3], xv.w, y3);
                    }
                    float yq = (y0 + y1) + (y2 + y3);
                    yq += __shfl_xor(yq, 16);        // quarter pairs
                    float y = yq + __shfl_xor(yq, 32);  // full row
                    alpha = em + Mj + A + __logf(y);
                    if (l < 16) xs[nxt][XIDX(row)] = __expf(alpha - Sn);
                    if (tid == 0) As[cur] = alpha;   // shift used at step t+1
                    A = Sn;
                    __syncthreads();                 // single barrier per step
                }
            }
        }

        // terminal logsumexp_j( alpha[j] + trans[STOP,j] ).
        // lanes l<16 of each wave hold 16 unique rows (others duplicate them).
        float term = (l < 16) ? (alpha + trans[TAG_STOP * KK + row]) : -1e30f;
        float m = term;
#pragma unroll
        for (int off = 8; off >= 1; off >>= 1) m = fmaxf(m, __shfl_xor(m, off));
        m = fmaxf(m, __shfl_xor(m, 16));
        m = fmaxf(m, __shfl_xor(m, 32));
        float s = (l < 16) ? __expf(term - m) : 0.f;
#pragma unroll
        for (int off = 8; off >= 1; off >>= 1) s += __shfl_xor(s, off);
        s += __shfl_xor(s, 16);
        s += __shfl_xor(s, 32);
        if (l == 0) { redm[w] = m; reds[w] = s; }
        __syncthreads();
        if (tid == 0) {
            float M2 = redm[0];
            for (int i = 1; i < 8; i++) M2 = fmaxf(M2, redm[i]);
            float S2 = 0.f;
            for (int i = 0; i < 8; i++) S2 += reds[i] * __expf(redm[i] - M2);
            fwd_out[b] = M2 + __logf(S2);
        }
    } else {
        // ---------------- gold path ----------------
        int b = blockIdx.x - BB;
        int len = lengths[b];
        const int* tg = tags + b * TT;
        const float* fb = feats + (size_t)b * TT * KK;
        float acc = 0.f;
        for (int i = tid; i <= len; i += 512) {
            int from = (i == 0) ? TAG_START : tg[i - 1];
            int to = (i < len) ? tg[i] : TAG_STOP;
            acc += trans[to * KK + from];
        }
        for (int t = tid; t < len; t += 512)
            acc += fb[(size_t)t * KK + tg[t]];
        __shared__ float sred[8];
#pragma unroll
        for (int off = 32; off >= 1; off >>= 1) acc += __shfl_xor(acc, off);
        if ((tid & 63) == 0) sred[tid >> 6] = acc;
        __syncthreads();
        if (tid == 0) {
            float s = 0.f;
            for (int i = 0; i < 8; i++) s += sred[i];
            gold_out[b] = s;
        }
    }
}

__global__ __launch_bounds__(512) void final_kernel(const float* __restrict__ fwd_s,
                                                    const float* __restrict__ gold_s,
                                                    float* __restrict__ out) {
    int tid = threadIdx.x;
    float v = fabsf(fwd_s[tid] - gold_s[tid]);
#pragma unroll
    for (int off = 32; off >= 1; off >>= 1) v += __shfl_xor(v, off);
    __shared__ float sred[8];
    if ((tid & 63) == 0) sred[tid >> 6] = v;
    __syncthreads();
    if (tid == 0) {
        float s = 0.f;
        for (int i = 0; i < 8; i++) s += sred[i];
        out[0] = s / (float)BB;
    }
}

extern "C" void kernel_launch(void* const* d_in, const int* in_sizes, int n_in,
                              void* d_out, int out_size, void* d_ws, size_t ws_size,
                              hipStream_t stream) {
    const float* feats = (const float*)d_in[0];
    const float* trans = (const float*)d_in[1];
    const int* tags = (const int*)d_in[2];
    const int* lengths = (const int*)d_in[3];

    float* ws = (float*)d_ws;
    float* fwdv = ws;
    float* goldv = ws + BB;

    fused_kernel<<<2 * BB, 512, 0, stream>>>(feats, trans, tags, lengths, fwdv, goldv);
    final_kernel<<<1, 512, 0, stream>>>(fwdv, goldv, (float*)d_out);
}